// Round 5
// baseline (227.294 us; speedup 1.0000x reference)
//
#include <hip/hip_runtime.h>
#include <hip/hip_bf16.h>

// GPT attention block on MI355X: qkv GEMM -> causal flash attn -> proj GEMM.
// B=2, T=2048, D=1024, H=16, dh=64.
// Attn: swapped-QK 32x32x16 MFMA, in-register softmax with exp2 (log2e folded
// into Q), v_cvt_pk_bf16_f32 P-pack (T12), defer-rescale (T13), setprio (T5),
// intra-block split-KV with bf16 LDS combine. V transposed by dedicated kernel.

typedef unsigned short u16;
typedef unsigned int u32;
typedef __attribute__((ext_vector_type(4))) float f32x4;
typedef __attribute__((ext_vector_type(16))) float f32x16;
typedef __attribute__((ext_vector_type(8))) short bf16x8;
typedef __attribute__((ext_vector_type(4))) int i32x4;

__device__ __forceinline__ u16 f2bf(float f) {
  unsigned u = __builtin_bit_cast(unsigned, f);
  u += 0x7FFFu + ((u >> 16) & 1u);
  return (u16)(u >> 16);
}

__device__ __forceinline__ u32 cvtpk(float lo, float hi) {
  u32 r;
  asm("v_cvt_pk_bf16_f32 %0, %1, %2" : "=v"(r) : "v"(lo), "v"(hi));
  return r;
}

__device__ __forceinline__ void gl_lds16(const u16* g, u16* l) {
  __builtin_amdgcn_global_load_lds(
      (const __attribute__((address_space(1))) void*)g,
      (__attribute__((address_space(3))) void*)l, 16, 0, 0);
}

// ---------------- cast fp32 -> bf16 (vectorized) ----------------
__global__ __launch_bounds__(256) void cast_bf16_kernel(const float* __restrict__ in,
                                                        u16* __restrict__ out, int n4) {
  int i = blockIdx.x * 256 + threadIdx.x;
  if (i < n4) {
    float4 f = reinterpret_cast<const float4*>(in)[i];
    ushort4 o;
    o.x = f2bf(f.x); o.y = f2bf(f.y); o.z = f2bf(f.z); o.w = f2bf(f.w);
    reinterpret_cast<ushort4*>(out)[i] = o;
  }
}

// ---------------- transpose + cast: in[R][C] f32 -> out[C][R] bf16 ----------------
__global__ __launch_bounds__(256) void transpose_cast(const float* __restrict__ in,
                                                      u16* __restrict__ out, int R, int C) {
  __shared__ float tile[32][33];
  const int c0 = blockIdx.x * 32, r0 = blockIdx.y * 32;
  const int tx = threadIdx.x, ty = threadIdx.y;  // block (32,8)
#pragma unroll
  for (int i = 0; i < 4; ++i)
    tile[ty + 8 * i][tx] = in[(size_t)(r0 + ty + 8 * i) * C + c0 + tx];
  __syncthreads();
#pragma unroll
  for (int i = 0; i < 4; ++i)
    out[(size_t)(c0 + ty + 8 * i) * R + r0 + tx] = f2bf(tile[tx][ty + 8 * i]);
}

// ---------------- bf16 GEMM 128x128: C = A[M][K] * Bt[N][K]^T + bias ----------------
// MODE 0: scatter epilogue to Qh (scaled by log2e/8), Kh, Vh  (all [B,H,T,dh] bf16)
// MODE 1: plain fp32 out
template <int MODE>
__global__ __launch_bounds__(256) void gemm_bf16(
    const u16* __restrict__ A, const u16* __restrict__ Bt, const float* __restrict__ bias,
    float* __restrict__ outF, u16* __restrict__ Qh, u16* __restrict__ Kh, u16* __restrict__ Vh,
    int N, int K) {
  __shared__ u16 As[128 * 32];
  __shared__ u16 Bs[128 * 32];
  const int tid = threadIdx.x;
  const int wave = tid >> 6, lane = tid & 63;
  const int kg = lane >> 4, rr = lane & 15;
  const int wm = wave >> 1, wn = wave & 1;
  // XCD-aware bijective swizzle (grid counts are multiples of 8)
  const int nwg = gridDim.x * gridDim.y;
  const int lin = blockIdx.y * gridDim.x + blockIdx.x;
  const int swz = (lin & 7) * (nwg >> 3) + (lin >> 3);
  const int bx = swz % gridDim.x, by = swz / gridDim.x;
  const int rowA0 = by * 128, colB0 = bx * 128;

  const f32x4 z4 = {0.f, 0.f, 0.f, 0.f};
  f32x4 acc[4][4];
#pragma unroll
  for (int i = 0; i < 4; ++i)
#pragma unroll
    for (int j = 0; j < 4; ++j) acc[i][j] = z4;

  const int r_st = tid >> 2;
  const int c_st = (tid & 3) * 8;

  for (int k0 = 0; k0 < K; k0 += 32) {
#pragma unroll
    for (int i = 0; i < 2; ++i) {
      gl_lds16(A + (size_t)(rowA0 + i * 64 + r_st) * K + k0 + c_st,
               As + (i * 256 + (wave << 6)) * 8);
      gl_lds16(Bt + (size_t)(colB0 + i * 64 + r_st) * K + k0 + c_st,
               Bs + (i * 256 + (wave << 6)) * 8);
    }
    __syncthreads();

    bf16x8 af[4], bfr[4];
#pragma unroll
    for (int mi = 0; mi < 4; ++mi)
      af[mi] = *reinterpret_cast<const bf16x8*>(&As[(wm * 64 + mi * 16 + rr) * 32 + kg * 8]);
#pragma unroll
    for (int ni = 0; ni < 4; ++ni)
      bfr[ni] = *reinterpret_cast<const bf16x8*>(&Bs[(wn * 64 + ni * 16 + rr) * 32 + kg * 8]);
#pragma unroll
    for (int mi = 0; mi < 4; ++mi)
#pragma unroll
      for (int ni = 0; ni < 4; ++ni)
        acc[mi][ni] = __builtin_amdgcn_mfma_f32_16x16x32_bf16(af[mi], bfr[ni], acc[mi][ni], 0, 0, 0);
    __syncthreads();
  }

  const float QS = 0.125f * 1.44269504088896f;  // fold 1/sqrt(dh) * log2(e)
#pragma unroll
  for (int mi = 0; mi < 4; ++mi) {
#pragma unroll
    for (int ni = 0; ni < 4; ++ni) {
      const int col = colB0 + wn * 64 + ni * 16 + rr;
      const float bcol = bias[col];
      f32x4 a = acc[mi][ni];
#pragma unroll
      for (int v = 0; v < 4; ++v) {
        const int row = rowA0 + wm * 64 + mi * 16 + kg * 4 + v;
        const float val = a[v] + bcol;
        if (MODE == 1) {
          outF[(size_t)row * N + col] = val;
        } else {
          const int b = row >> 11, t = row & 2047;
          const int which = col >> 10, d = col & 1023;
          const int h = d >> 6, dd = d & 63;
          const size_t idx = (((size_t)(b * 16 + h)) * 2048 + t) * 64 + dd;
          if (which == 0)
            Qh[idx] = f2bf(val * QS);
          else if (which == 1)
            Kh[idx] = f2bf(val);
          else
            Vh[idx] = f2bf(val);
        }
      }
    }
  }
}

// ---------------- V transpose: Vh[bh][t][dd] -> VhT[bh][dd][t] ----------------
__global__ __launch_bounds__(256) void transpose_v(const u16* __restrict__ Vh,
                                                   u16* __restrict__ VhT) {
  __shared__ u16 tile[64][72];
  const int tid = threadIdx.x;
  const int t0 = blockIdx.x * 64;
  const int bh = blockIdx.y;
  const u16* src = Vh + ((size_t)bh * 2048 + t0) * 64;
  {
    const int ty = tid >> 2, tx = (tid & 3) * 16;
    *reinterpret_cast<bf16x8*>(&tile[ty][tx]) =
        *reinterpret_cast<const bf16x8*>(src + ty * 64 + tx);
    *reinterpret_cast<bf16x8*>(&tile[ty][tx + 8]) =
        *reinterpret_cast<const bf16x8*>(src + ty * 64 + tx + 8);
  }
  __syncthreads();
  {
    const int dd = tid >> 2, toff = (tid & 3) * 16;
    bf16x8 v0, v1;
#pragma unroll
    for (int j = 0; j < 8; ++j) v0[j] = (short)tile[toff + j][dd];
#pragma unroll
    for (int j = 0; j < 8; ++j) v1[j] = (short)tile[toff + 8 + j][dd];
    u16* dst = VhT + ((size_t)bh * 64 + dd) * 2048 + t0 + toff;
    *reinterpret_cast<bf16x8*>(dst) = v0;
    *reinterpret_cast<bf16x8*>(dst + 8) = v1;
  }
}

// ---------------- causal flash attention, split-KV within block ----------------
// Block = (bh, qtile of 32 q-rows). 4 waves split the KV range; bf16 LDS combine.
// S is in log2 domain (Q pre-scaled by log2e/8): softmax via v_exp (2^x).
__global__ __launch_bounds__(256) void attn_fwd(const u16* __restrict__ Qh,
                                                const u16* __restrict__ Kh,
                                                const u16* __restrict__ VhT,
                                                u16* __restrict__ Ab) {
  __shared__ u16 Olq[4][32][72];   // [wave][q][dh 64 + pad], bf16 partials
  __shared__ float Ml[4][2][32];   // [wave][{m,l}][q]
  const int tid = threadIdx.x;
  const int wave = tid >> 6, lane = tid & 63;
  const int lq = lane & 31, hi = lane >> 5;
  const int blk = blockIdx.x;
  const int qi = blk >> 5;          // 0..63, longest qtile first
  const int bh = blk & 31;
  const int qtile = 63 - qi;
  const int q0 = qtile * 32;
  const int myq = q0 + lq;
  const size_t kvbase = (size_t)bh * 2048;

  const int n64 = (q0 + 32 + 63) >> 6;
  const int base = n64 >> 2, rem = n64 & 3;
  const int cnt = base + (wave < rem ? 1 : 0);
  const int start = wave * base + (wave < rem ? wave : rem);

  // Q as B-operand (pre-scaled): col=q, k = hi*8 + j (+16*ks over dh=64)
  bf16x8 qf[4];
  {
    const u16* qptr = Qh + (kvbase + q0 + lq) * 64 + hi * 8;
#pragma unroll
    for (int ks = 0; ks < 4; ++ks)
      qf[ks] = *reinterpret_cast<const bf16x8*>(qptr + ks * 16);
  }

  f32x16 oA, oB;  // O^T partial: dh [0,32) / [32,64); col=q, row=dh'
#pragma unroll
  for (int i = 0; i < 16; ++i) { oA[i] = 0.f; oB[i] = 0.f; }
  float m = -1e30f, l = 0.f;

  for (int kvb = start; kvb < start + cnt; ++kvb) {
    const int kv0 = kvb * 64;

    const u16* kptr = Kh + (kvbase + kv0 + lq) * 64 + hi * 8;
    bf16x8 kfA[4], kfB[4];
#pragma unroll
    for (int ks = 0; ks < 4; ++ks) {
      kfA[ks] = *reinterpret_cast<const bf16x8*>(kptr + ks * 16);
      kfB[ks] = *reinterpret_cast<const bf16x8*>(kptr + 2048 + ks * 16);  // +32 rows
    }

    // S^T = K Q^T (log2 domain): col=q, row kv = (r&3)+8*(r>>2)+4*hi
    f32x16 sA, sB;
#pragma unroll
    for (int i = 0; i < 16; ++i) { sA[i] = 0.f; sB[i] = 0.f; }
    __builtin_amdgcn_s_setprio(1);
#pragma unroll
    for (int ks = 0; ks < 4; ++ks)
      sA = __builtin_amdgcn_mfma_f32_32x32x16_bf16(kfA[ks], qf[ks], sA, 0, 0, 0);
#pragma unroll
    for (int ks = 0; ks < 4; ++ks)
      sB = __builtin_amdgcn_mfma_f32_32x32x16_bf16(kfB[ks], qf[ks], sB, 0, 0, 0);
    __builtin_amdgcn_s_setprio(0);

    if (kvb == n64 - 1) {  // causal mask, last global block only
#pragma unroll
      for (int r = 0; r < 16; ++r) {
        const int kvA = kv0 + (r & 3) + 8 * (r >> 2) + 4 * hi;
        if (kvA > myq) sA[r] = -1e30f;
        if (kvA + 32 > myq) sB[r] = -1e30f;
      }
    }

    // online softmax (log2): lane owns one q-column, partner lane^32
    float pmax = -1e30f;
#pragma unroll
    for (int r = 0; r < 16; ++r) pmax = fmaxf(pmax, fmaxf(sA[r], sB[r]));
    pmax = fmaxf(pmax, __shfl_xor(pmax, 32));
    if (!__all(pmax - m <= 8.0f)) {  // T13 defer-rescale (p bounded by 2^8)
      const float mn = fmaxf(m, pmax);
      const float sc = __builtin_amdgcn_exp2f(m - mn);
      l *= sc;
      oA *= sc;
      oB *= sc;
      m = mn;
    }
    float rsum = 0.f;
#pragma unroll
    for (int r = 0; r < 16; ++r) {
      const float pa = __builtin_amdgcn_exp2f(sA[r] - m);
      const float pb = __builtin_amdgcn_exp2f(sB[r] - m);
      sA[r] = pa; sB[r] = pb;
      rsum += pa + pb;
    }
    rsum += __shfl_xor(rsum, 32);
    l += rsum;

    // V loads (sunk here to cap register pressure)
    const u16* vptr = VhT + ((size_t)bh * 64 + lq) * 2048 + kv0 + hi * 8;
    bf16x8 vfA[4], vfB[4];
#pragma unroll
    for (int ks = 0; ks < 4; ++ks) {
      vfA[ks] = *reinterpret_cast<const bf16x8*>(vptr + ks * 16);
      vfB[ks] = *reinterpret_cast<const bf16x8*>(vptr + 32 * 2048 + ks * 16);
    }

    // P^T -> bf16 B-operand frags: v_cvt_pk + permlane32_swap (T12)
    u32 pkA[8], pkB[8];
#pragma unroll
    for (int i = 0; i < 8; ++i) {
      pkA[i] = cvtpk(sA[2 * i], sA[2 * i + 1]);
      pkB[i] = cvtpk(sB[2 * i], sB[2 * i + 1]);
    }
    bf16x8 pf[4];
    {
      auto w0 = __builtin_amdgcn_permlane32_swap(pkA[0], pkA[2], false, false);
      auto w1 = __builtin_amdgcn_permlane32_swap(pkA[1], pkA[3], false, false);
      i32x4 t0 = {(int)w0[0], (int)w1[0], (int)w0[1], (int)w1[1]};
      pf[0] = __builtin_bit_cast(bf16x8, t0);
      auto w2 = __builtin_amdgcn_permlane32_swap(pkA[4], pkA[6], false, false);
      auto w3 = __builtin_amdgcn_permlane32_swap(pkA[5], pkA[7], false, false);
      i32x4 t1 = {(int)w2[0], (int)w3[0], (int)w2[1], (int)w3[1]};
      pf[1] = __builtin_bit_cast(bf16x8, t1);
      auto w4 = __builtin_amdgcn_permlane32_swap(pkB[0], pkB[2], false, false);
      auto w5 = __builtin_amdgcn_permlane32_swap(pkB[1], pkB[3], false, false);
      i32x4 t2 = {(int)w4[0], (int)w5[0], (int)w4[1], (int)w5[1]};
      pf[2] = __builtin_bit_cast(bf16x8, t2);
      auto w6 = __builtin_amdgcn_permlane32_swap(pkB[4], pkB[6], false, false);
      auto w7 = __builtin_amdgcn_permlane32_swap(pkB[5], pkB[7], false, false);
      i32x4 t3 = {(int)w6[0], (int)w7[0], (int)w6[1], (int)w7[1]};
      pf[3] = __builtin_bit_cast(bf16x8, t3);
    }

    // O^T += V^T P^T
    __builtin_amdgcn_s_setprio(1);
#pragma unroll
    for (int ks = 0; ks < 4; ++ks)
      oA = __builtin_amdgcn_mfma_f32_32x32x16_bf16(vfA[ks], pf[ks], oA, 0, 0, 0);
#pragma unroll
    for (int ks = 0; ks < 4; ++ks)
      oB = __builtin_amdgcn_mfma_f32_32x32x16_bf16(vfB[ks], pf[ks], oB, 0, 0, 0);
    __builtin_amdgcn_s_setprio(0);
  }

  // ---- write partials (bf16, vectorized) ----
  if (hi == 0) {
    Ml[wave][0][lq] = m;
    Ml[wave][1][lq] = l;
  }
  {
    u32* orow = reinterpret_cast<u32*>(&Olq[wave][lq][0]);
#pragma unroll
    for (int qd = 0; qd < 4; ++qd) {
      const int dh0 = 8 * qd + 4 * hi;  // even -> u32-aligned
      orow[(dh0 >> 1) + 0] = cvtpk(oA[4 * qd + 0], oA[4 * qd + 1]);
      orow[(dh0 >> 1) + 1] = cvtpk(oA[4 * qd + 2], oA[4 * qd + 3]);
      orow[((dh0 + 32) >> 1) + 0] = cvtpk(oB[4 * qd + 0], oB[4 * qd + 1]);
      orow[((dh0 + 32) >> 1) + 1] = cvtpk(oB[4 * qd + 2], oB[4 * qd + 3]);
    }
  }
  __syncthreads();

  // ---- combine: thread -> (q-col = tid>>3, dh0 = (tid&7)*8) ----
  const int col = tid >> 3;
  const int dh0 = (tid & 7) * 8;
  float M = -1e30f;
  float mw[4];
#pragma unroll
  for (int w = 0; w < 4; ++w) { mw[w] = Ml[w][0][col]; M = fmaxf(M, mw[w]); }
  float lsum = 0.f;
  float scw[4];
#pragma unroll
  for (int w = 0; w < 4; ++w) {
    scw[w] = __builtin_amdgcn_exp2f(mw[w] - M);
    lsum += scw[w] * Ml[w][1][col];
  }
  const float inv = 1.0f / lsum;
  float acc8[8];
#pragma unroll
  for (int i = 0; i < 8; ++i) acc8[i] = 0.f;
#pragma unroll
  for (int w = 0; w < 4; ++w) {
    bf16x8 ov = *reinterpret_cast<const bf16x8*>(&Olq[w][col][dh0]);
#pragma unroll
    for (int i = 0; i < 8; ++i) {
      const float f = __builtin_bit_cast(float, ((u32)(u16)ov[i]) << 16);
      acc8[i] += scw[w] * f;
    }
  }
  const int b = bh >> 4, h = bh & 15;
  bf16x8 outv;
#pragma unroll
  for (int i = 0; i < 8; ++i) outv[i] = (short)f2bf(acc8[i] * inv);
  *reinterpret_cast<bf16x8*>(Ab + ((size_t)b * 2048 + q0 + col) * 1024 + h * 64 + dh0) = outv;
}

extern "C" void kernel_launch(void* const* d_in, const int* in_sizes, int n_in,
                              void* d_out, int out_size, void* d_ws, size_t ws_size,
                              hipStream_t stream) {
  const float* x      = (const float*)d_in[0];
  const float* W_attn = (const float*)d_in[1];
  const float* b_attn = (const float*)d_in[2];
  const float* W_proj = (const float*)d_in[3];
  const float* b_proj = (const float*)d_in[4];
  float* out = (float*)d_out;

  u16* xb  = (u16*)d_ws;                      // [4096][1024] bf16
  u16* Wat = xb + (size_t)4096 * 1024;        // [3072][1024] bf16 (W_attn^T)
  u16* Wpt = Wat + (size_t)3072 * 1024;       // [1024][1024] bf16 (W_proj^T)
  u16* Qh  = Wpt + (size_t)1024 * 1024;       // [2,16,2048,64] bf16 (log2e/8-scaled)
  u16* Kh  = Qh + (size_t)4194304;            // [2,16,2048,64] bf16
  u16* VhT = Kh + (size_t)4194304;            // [2,16,64,2048] bf16
  u16* Ab  = VhT + (size_t)4194304;           // [4096][1024] bf16
  u16* Vh  = Ab;                              // [2,16,2048,64] bf16 (reuses Ab slot:
                                              //  consumed by transpose_v before attn writes Ab)

  cast_bf16_kernel<<<4096, 256, 0, stream>>>(x, xb, 4096 * 1024 / 4);
  transpose_cast<<<dim3(96, 32), dim3(32, 8), 0, stream>>>(W_attn, Wat, 1024, 3072);
  transpose_cast<<<dim3(32, 32), dim3(32, 8), 0, stream>>>(W_proj, Wpt, 1024, 1024);
  gemm_bf16<0><<<dim3(24, 32), 256, 0, stream>>>(xb, Wat, b_attn, nullptr, Qh, Kh, Vh,
                                                 3072, 1024);
  transpose_v<<<dim3(32, 32), 256, 0, stream>>>(Vh, VhT);
  attn_fwd<<<dim3(2048), 256, 0, stream>>>(Qh, Kh, VhT, Ab);
  gemm_bf16<1><<<dim3(8, 32), 256, 0, stream>>>(Ab, Wpt, b_proj, out, nullptr, nullptr, nullptr,
                                                1024, 1024);
}

// Round 7
// 218.151 us; speedup vs baseline: 1.0419x; 1.0419x over previous
//
#include <hip/hip_runtime.h>
#include <hip/hip_bf16.h>

// GPT attention block on MI355X: qkv GEMM -> causal flash attn -> proj GEMM.
// B=2, T=2048, D=1024, H=16, dh=64.
// Attn: swapped-QK 32x32x16 MFMA, in-register exp2 softmax, cvt_pk P-pack (T12),
// defer-rescale (T13), setprio (T5), split-KV + LDS combine, and (new R6)
// software-pipelined K/V loads: K register-double-buffered, V issued early (T14).

typedef unsigned short u16;
typedef unsigned int u32;
typedef __attribute__((ext_vector_type(4))) float f32x4;
typedef __attribute__((ext_vector_type(16))) float f32x16;
typedef __attribute__((ext_vector_type(8))) short bf16x8;
typedef __attribute__((ext_vector_type(4))) int i32x4;

__device__ __forceinline__ u16 f2bf(float f) {
  unsigned u = __builtin_bit_cast(unsigned, f);
  u += 0x7FFFu + ((u >> 16) & 1u);
  return (u16)(u >> 16);
}

__device__ __forceinline__ u32 cvtpk(float lo, float hi) {
  u32 r;
  asm("v_cvt_pk_bf16_f32 %0, %1, %2" : "=v"(r) : "v"(lo), "v"(hi));
  return r;
}

__device__ __forceinline__ void gl_lds16(const u16* g, u16* l) {
  __builtin_amdgcn_global_load_lds(
      (const __attribute__((address_space(1))) void*)g,
      (__attribute__((address_space(3))) void*)l, 16, 0, 0);
}

// ---------------- cast fp32 -> bf16 (vectorized) ----------------
__global__ __launch_bounds__(256) void cast_bf16_kernel(const float* __restrict__ in,
                                                        u16* __restrict__ out, int n4) {
  int i = blockIdx.x * 256 + threadIdx.x;
  if (i < n4) {
    float4 f = reinterpret_cast<const float4*>(in)[i];
    ushort4 o;
    o.x = f2bf(f.x); o.y = f2bf(f.y); o.z = f2bf(f.z); o.w = f2bf(f.w);
    reinterpret_cast<ushort4*>(out)[i] = o;
  }
}

// ---------------- transpose + cast: in[R][C] f32 -> out[C][R] bf16 ----------------
__global__ __launch_bounds__(256) void transpose_cast(const float* __restrict__ in,
                                                      u16* __restrict__ out, int R, int C) {
  __shared__ float tile[32][33];
  const int c0 = blockIdx.x * 32, r0 = blockIdx.y * 32;
  const int tx = threadIdx.x, ty = threadIdx.y;  // block (32,8)
#pragma unroll
  for (int i = 0; i < 4; ++i)
    tile[ty + 8 * i][tx] = in[(size_t)(r0 + ty + 8 * i) * C + c0 + tx];
  __syncthreads();
#pragma unroll
  for (int i = 0; i < 4; ++i)
    out[(size_t)(c0 + ty + 8 * i) * R + r0 + tx] = f2bf(tile[tx][ty + 8 * i]);
}

// ---------------- bf16 GEMM 128x128: qkv projection, scatter epilogue ----------------
__global__ __launch_bounds__(256) void gemm_qkv(
    const u16* __restrict__ A, const u16* __restrict__ Bt, const float* __restrict__ bias,
    u16* __restrict__ Qh, u16* __restrict__ Kh, u16* __restrict__ Vh, int K) {
  __shared__ u16 As[128 * 32];
  __shared__ u16 Bs[128 * 32];
  const int tid = threadIdx.x;
  const int wave = tid >> 6, lane = tid & 63;
  const int kg = lane >> 4, rr = lane & 15;
  const int wm = wave >> 1, wn = wave & 1;
  const int nwg = gridDim.x * gridDim.y;  // 768, %8==0
  const int lin = blockIdx.y * gridDim.x + blockIdx.x;
  const int swz = (lin & 7) * (nwg >> 3) + (lin >> 3);
  const int bx = swz % gridDim.x, by = swz / gridDim.x;
  const int rowA0 = by * 128, colB0 = bx * 128;

  const f32x4 z4 = {0.f, 0.f, 0.f, 0.f};
  f32x4 acc[4][4];
#pragma unroll
  for (int i = 0; i < 4; ++i)
#pragma unroll
    for (int j = 0; j < 4; ++j) acc[i][j] = z4;

  const int r_st = tid >> 2;
  const int c_st = (tid & 3) * 8;

  for (int k0 = 0; k0 < K; k0 += 32) {
#pragma unroll
    for (int i = 0; i < 2; ++i) {
      gl_lds16(A + (size_t)(rowA0 + i * 64 + r_st) * K + k0 + c_st,
               As + (i * 256 + (wave << 6)) * 8);
      gl_lds16(Bt + (size_t)(colB0 + i * 64 + r_st) * K + k0 + c_st,
               Bs + (i * 256 + (wave << 6)) * 8);
    }
    __syncthreads();

    bf16x8 af[4], bfr[4];
#pragma unroll
    for (int mi = 0; mi < 4; ++mi)
      af[mi] = *reinterpret_cast<const bf16x8*>(&As[(wm * 64 + mi * 16 + rr) * 32 + kg * 8]);
#pragma unroll
    for (int ni = 0; ni < 4; ++ni)
      bfr[ni] = *reinterpret_cast<const bf16x8*>(&Bs[(wn * 64 + ni * 16 + rr) * 32 + kg * 8]);
#pragma unroll
    for (int mi = 0; mi < 4; ++mi)
#pragma unroll
      for (int ni = 0; ni < 4; ++ni)
        acc[mi][ni] = __builtin_amdgcn_mfma_f32_16x16x32_bf16(af[mi], bfr[ni], acc[mi][ni], 0, 0, 0);
    __syncthreads();
  }

  const float QS = 0.125f * 1.44269504088896f;  // fold 1/sqrt(dh) * log2(e)
#pragma unroll
  for (int mi = 0; mi < 4; ++mi) {
#pragma unroll
    for (int ni = 0; ni < 4; ++ni) {
      const int col = colB0 + wn * 64 + ni * 16 + rr;
      const float bcol = bias[col];
      f32x4 a = acc[mi][ni];
#pragma unroll
      for (int v = 0; v < 4; ++v) {
        const int row = rowA0 + wm * 64 + mi * 16 + kg * 4 + v;
        const float val = a[v] + bcol;
        const int b = row >> 11, t = row & 2047;
        const int which = col >> 10, d = col & 1023;
        const int h = d >> 6, dd = d & 63;
        const size_t idx = (((size_t)(b * 16 + h)) * 2048 + t) * 64 + dd;
        if (which == 0)
          Qh[idx] = f2bf(val * QS);
        else if (which == 1)
          Kh[idx] = f2bf(val);
        else
          Vh[idx] = f2bf(val);
      }
    }
  }
}

// ---------------- bf16 GEMM 128x64: proj, fp32 out + bias ----------------
__global__ __launch_bounds__(256) void gemm_proj(
    const u16* __restrict__ A, const u16* __restrict__ Bt, const float* __restrict__ bias,
    float* __restrict__ outF, int N, int K) {
  __shared__ u16 As[128 * 32];
  __shared__ u16 Bs[64 * 32];
  const int tid = threadIdx.x;
  const int wave = tid >> 6, lane = tid & 63;
  const int kg = lane >> 4, rr = lane & 15;
  const int nwg = gridDim.x * gridDim.y;  // 512, %8==0
  const int lin = blockIdx.y * gridDim.x + blockIdx.x;
  const int swz = (lin & 7) * (nwg >> 3) + (lin >> 3);
  const int bx = swz % gridDim.x, by = swz / gridDim.x;
  const int rowA0 = by * 128, colB0 = bx * 64;

  const f32x4 z4 = {0.f, 0.f, 0.f, 0.f};
  f32x4 acc[2][4];
#pragma unroll
  for (int i = 0; i < 2; ++i)
#pragma unroll
    for (int j = 0; j < 4; ++j) acc[i][j] = z4;

  const int r_st = tid >> 2;
  const int c_st = (tid & 3) * 8;

  for (int k0 = 0; k0 < K; k0 += 32) {
#pragma unroll
    for (int i = 0; i < 2; ++i)
      gl_lds16(A + (size_t)(rowA0 + i * 64 + r_st) * K + k0 + c_st,
               As + (i * 256 + (wave << 6)) * 8);
    gl_lds16(Bt + (size_t)(colB0 + r_st) * K + k0 + c_st, Bs + (wave << 6) * 8);
    __syncthreads();

    bf16x8 af[2], bfr[4];
#pragma unroll
    for (int mi = 0; mi < 2; ++mi)
      af[mi] = *reinterpret_cast<const bf16x8*>(&As[(wave * 32 + mi * 16 + rr) * 32 + kg * 8]);
#pragma unroll
    for (int ni = 0; ni < 4; ++ni)
      bfr[ni] = *reinterpret_cast<const bf16x8*>(&Bs[(ni * 16 + rr) * 32 + kg * 8]);
#pragma unroll
    for (int mi = 0; mi < 2; ++mi)
#pragma unroll
      for (int ni = 0; ni < 4; ++ni)
        acc[mi][ni] = __builtin_amdgcn_mfma_f32_16x16x32_bf16(af[mi], bfr[ni], acc[mi][ni], 0, 0, 0);
    __syncthreads();
  }

#pragma unroll
  for (int mi = 0; mi < 2; ++mi) {
#pragma unroll
    for (int ni = 0; ni < 4; ++ni) {
      const int col = colB0 + ni * 16 + rr;
      const float bcol = bias[col];
      f32x4 a = acc[mi][ni];
#pragma unroll
      for (int v = 0; v < 4; ++v) {
        const int row = rowA0 + wave * 32 + mi * 16 + kg * 4 + v;
        outF[(size_t)row * N + col] = a[v] + bcol;
      }
    }
  }
}

// ---------------- V transpose: Vh[bh][t][dd] -> VhT[bh][dd][t] ----------------
__global__ __launch_bounds__(256) void transpose_v(const u16* __restrict__ Vh,
                                                   u16* __restrict__ VhT) {
  __shared__ u16 tile[64][72];
  const int tid = threadIdx.x;
  const int t0 = blockIdx.x * 64;
  const int bh = blockIdx.y;
  const u16* src = Vh + ((size_t)bh * 2048 + t0) * 64;
  {
    const int ty = tid >> 2, tx = (tid & 3) * 16;
    *reinterpret_cast<bf16x8*>(&tile[ty][tx]) =
        *reinterpret_cast<const bf16x8*>(src + ty * 64 + tx);
    *reinterpret_cast<bf16x8*>(&tile[ty][tx + 8]) =
        *reinterpret_cast<const bf16x8*>(src + ty * 64 + tx + 8);
  }
  __syncthreads();
  {
    const int dd = tid >> 2, toff = (tid & 3) * 16;
    bf16x8 v0, v1;
#pragma unroll
    for (int j = 0; j < 8; ++j) v0[j] = (short)tile[toff + j][dd];
#pragma unroll
    for (int j = 0; j < 8; ++j) v1[j] = (short)tile[toff + 8 + j][dd];
    u16* dst = VhT + ((size_t)bh * 64 + dd) * 2048 + t0 + toff;
    *reinterpret_cast<bf16x8*>(dst) = v0;
    *reinterpret_cast<bf16x8*>(dst + 8) = v1;
  }
}

// ---------------- attn: one pipeline step (forceinline so arrays stay in regs) ----
__device__ __forceinline__ void load_k(const u16* kptr, bf16x8 (&kA)[4], bf16x8 (&kB)[4]) {
#pragma unroll
  for (int ks = 0; ks < 4; ++ks) {
    kA[ks] = *reinterpret_cast<const bf16x8*>(kptr + ks * 16);
    kB[ks] = *reinterpret_cast<const bf16x8*>(kptr + 2048 + ks * 16);
  }
}

__device__ __forceinline__ void attn_step(
    int kvb, int n64, int myq, int hi, const u16* vbase,
    const bf16x8 (&qf)[4], const bf16x8 (&kA)[4], const bf16x8 (&kB)[4],
    f32x16& oA, f32x16& oB, float& m, float& l) {
  // V loads issued FIRST: latency hides under QK^T + softmax
  bf16x8 vfA[4], vfB[4];
  const u16* vp = vbase + kvb * 64;
#pragma unroll
  for (int ks = 0; ks < 4; ++ks) {
    vfA[ks] = *reinterpret_cast<const bf16x8*>(vp + ks * 16);
    vfB[ks] = *reinterpret_cast<const bf16x8*>(vp + 32 * 2048 + ks * 16);
  }

  // S^T = K Q^T (log2 domain): col=q, row kv = (r&3)+8*(r>>2)+4*hi
  f32x16 sA, sB;
#pragma unroll
  for (int i = 0; i < 16; ++i) { sA[i] = 0.f; sB[i] = 0.f; }
  __builtin_amdgcn_s_setprio(1);
#pragma unroll
  for (int ks = 0; ks < 4; ++ks)
    sA = __builtin_amdgcn_mfma_f32_32x32x16_bf16(kA[ks], qf[ks], sA, 0, 0, 0);
#pragma unroll
  for (int ks = 0; ks < 4; ++ks)
    sB = __builtin_amdgcn_mfma_f32_32x32x16_bf16(kB[ks], qf[ks], sB, 0, 0, 0);
  __builtin_amdgcn_s_setprio(0);

  if (kvb == n64 - 1) {  // causal mask, last global block only
    const int kv0 = kvb * 64;
#pragma unroll
    for (int r = 0; r < 16; ++r) {
      const int kvA = kv0 + (r & 3) + 8 * (r >> 2) + 4 * hi;
      if (kvA > myq) sA[r] = -1e30f;
      if (kvA + 32 > myq) sB[r] = -1e30f;
    }
  }

  // online softmax (log2 domain); lane owns one q-column, partner lane^32
  float pmax = -1e30f;
#pragma unroll
  for (int r = 0; r < 16; ++r) pmax = fmaxf(pmax, fmaxf(sA[r], sB[r]));
  pmax = fmaxf(pmax, __shfl_xor(pmax, 32));
  if (!__all(pmax - m <= 8.0f)) {  // T13 defer-rescale (p bounded by 2^8)
    const float mn = fmaxf(m, pmax);
    const float sc = __builtin_amdgcn_exp2f(m - mn);
    l *= sc;
    oA *= sc;
    oB *= sc;
    m = mn;
  }
  float rsum = 0.f;
#pragma unroll
  for (int r = 0; r < 16; ++r) {
    const float pa = __builtin_amdgcn_exp2f(sA[r] - m);
    const float pb = __builtin_amdgcn_exp2f(sB[r] - m);
    sA[r] = pa; sB[r] = pb;
    rsum += pa + pb;
  }
  rsum += __shfl_xor(rsum, 32);
  l += rsum;

  // P^T -> bf16 B-operand frags: v_cvt_pk + permlane32_swap (T12)
  u32 pkA[8], pkB[8];
#pragma unroll
  for (int i = 0; i < 8; ++i) {
    pkA[i] = cvtpk(sA[2 * i], sA[2 * i + 1]);
    pkB[i] = cvtpk(sB[2 * i], sB[2 * i + 1]);
  }
  bf16x8 pf[4];
  {
    auto w0 = __builtin_amdgcn_permlane32_swap(pkA[0], pkA[2], false, false);
    auto w1 = __builtin_amdgcn_permlane32_swap(pkA[1], pkA[3], false, false);
    i32x4 t0 = {(int)w0[0], (int)w1[0], (int)w0[1], (int)w1[1]};
    pf[0] = __builtin_bit_cast(bf16x8, t0);
    auto w2 = __builtin_amdgcn_permlane32_swap(pkA[4], pkA[6], false, false);
    auto w3 = __builtin_amdgcn_permlane32_swap(pkA[5], pkA[7], false, false);
    i32x4 t1 = {(int)w2[0], (int)w3[0], (int)w2[1], (int)w3[1]};
    pf[1] = __builtin_bit_cast(bf16x8, t1);
    auto w4 = __builtin_amdgcn_permlane32_swap(pkB[0], pkB[2], false, false);
    auto w5 = __builtin_amdgcn_permlane32_swap(pkB[1], pkB[3], false, false);
    i32x4 t2 = {(int)w4[0], (int)w5[0], (int)w4[1], (int)w5[1]};
    pf[2] = __builtin_bit_cast(bf16x8, t2);
    auto w6 = __builtin_amdgcn_permlane32_swap(pkB[4], pkB[6], false, false);
    auto w7 = __builtin_amdgcn_permlane32_swap(pkB[5], pkB[7], false, false);
    i32x4 t3 = {(int)w6[0], (int)w7[0], (int)w6[1], (int)w7[1]};
    pf[3] = __builtin_bit_cast(bf16x8, t3);
  }

  // O^T += V^T P^T
  __builtin_amdgcn_s_setprio(1);
#pragma unroll
  for (int ks = 0; ks < 4; ++ks)
    oA = __builtin_amdgcn_mfma_f32_32x32x16_bf16(vfA[ks], pf[ks], oA, 0, 0, 0);
#pragma unroll
  for (int ks = 0; ks < 4; ++ks)
    oB = __builtin_amdgcn_mfma_f32_32x32x16_bf16(vfB[ks], pf[ks], oB, 0, 0, 0);
  __builtin_amdgcn_s_setprio(0);
}

// ---------------- causal flash attention, split-KV + pipelined loads ----------------
__global__ __launch_bounds__(256, 2) void attn_fwd(const u16* __restrict__ Qh,
                                                   const u16* __restrict__ Kh,
                                                   const u16* __restrict__ VhT,
                                                   u16* __restrict__ Ab) {
  __shared__ u16 Olq[4][32][80];   // [wave][q][dh 64 + pad16], bf16 partials
  __shared__ float Ml[4][2][32];   // [wave][{m,l}][q]
  const int tid = threadIdx.x;
  const int wave = tid >> 6, lane = tid & 63;
  const int lq = lane & 31, hi = lane >> 5;
  const int blk = blockIdx.x;
  const int qi = blk >> 5;          // 0..63, longest qtile first
  const int bh = blk & 31;
  const int qtile = 63 - qi;
  const int q0 = qtile * 32;
  const int myq = q0 + lq;
  const size_t kvbase = (size_t)bh * 2048;

  const int n64 = (q0 + 32 + 63) >> 6;
  const int base = n64 >> 2, rem = n64 & 3;
  const int cnt = base + (wave < rem ? 1 : 0);
  const int start = wave * base + (wave < rem ? wave : rem);
  const int end = start + cnt;

  // Q as B-operand (pre-scaled by log2e/8): col=q, k = hi*8 + j (+16*ks)
  bf16x8 qf[4];
  {
    const u16* qptr = Qh + (kvbase + q0 + lq) * 64 + hi * 8;
#pragma unroll
    for (int ks = 0; ks < 4; ++ks)
      qf[ks] = *reinterpret_cast<const bf16x8*>(qptr + ks * 16);
  }

  f32x16 oA, oB;
#pragma unroll
  for (int i = 0; i < 16; ++i) { oA[i] = 0.f; oB[i] = 0.f; }
  float m = -1e30f, l = 0.f;

  const u16* kbase = Kh + (kvbase + lq) * 64 + hi * 8;            // + kvb*4096
  const u16* vbase = VhT + ((size_t)bh * 64 + lq) * 2048 + hi * 8;  // + kvb*64

  // software pipeline: K double-buffered in registers, 2-phase static unroll
  bf16x8 kA0[4], kB0[4], kA1[4], kB1[4];
  int kvb = start;
  if (kvb < end) {
    load_k(kbase + (size_t)kvb * 4096, kA0, kB0);
    while (true) {
      if (kvb + 1 < end) load_k(kbase + (size_t)(kvb + 1) * 4096, kA1, kB1);
      attn_step(kvb, n64, myq, hi, vbase, qf, kA0, kB0, oA, oB, m, l);
      if (++kvb >= end) break;
      if (kvb + 1 < end) load_k(kbase + (size_t)(kvb + 1) * 4096, kA0, kB0);
      attn_step(kvb, n64, myq, hi, vbase, qf, kA1, kB1, oA, oB, m, l);
      if (++kvb >= end) break;
    }
  }

  // ---- write partials (bf16, vectorized) ----
  if (hi == 0) {
    Ml[wave][0][lq] = m;
    Ml[wave][1][lq] = l;
  }
  {
    u32* orow = reinterpret_cast<u32*>(&Olq[wave][lq][0]);
#pragma unroll
    for (int qd = 0; qd < 4; ++qd) {
      const int dh0 = 8 * qd + 4 * hi;  // even -> u32-aligned
      orow[(dh0 >> 1) + 0] = cvtpk(oA[4 * qd + 0], oA[4 * qd + 1]);
      orow[(dh0 >> 1) + 1] = cvtpk(oA[4 * qd + 2], oA[4 * qd + 3]);
      orow[((dh0 + 32) >> 1) + 0] = cvtpk(oB[4 * qd + 0], oB[4 * qd + 1]);
      orow[((dh0 + 32) >> 1) + 1] = cvtpk(oB[4 * qd + 2], oB[4 * qd + 3]);
    }
  }
  __syncthreads();

  // ---- combine: thread -> (q-col = tid>>3, dh0 = (tid&7)*8) ----
  const int col = tid >> 3;
  const int dh0 = (tid & 7) * 8;
  float M = -1e30f;
  float mw[4];
#pragma unroll
  for (int w = 0; w < 4; ++w) { mw[w] = Ml[w][0][col]; M = fmaxf(M, mw[w]); }
  float lsum = 0.f;
  float scw[4];
#pragma unroll
  for (int w = 0; w < 4; ++w) {
    scw[w] = __builtin_amdgcn_exp2f(mw[w] - M);
    lsum += scw[w] * Ml[w][1][col];
  }
  const float inv = 1.0f / lsum;
  float acc8[8];
#pragma unroll
  for (int i = 0; i < 8; ++i) acc8[i] = 0.f;
#pragma unroll
  for (int w = 0; w < 4; ++w) {
    bf16x8 ov = *reinterpret_cast<const bf16x8*>(&Olq[w][col][dh0]);
#pragma unroll
    for (int i = 0; i < 8; ++i) {
      const float f = __builtin_bit_cast(float, ((u32)(u16)ov[i]) << 16);
      acc8[i] += scw[w] * f;
    }
  }
  const int b = bh >> 4, h = bh & 15;
  bf16x8 outv;
#pragma unroll
  for (int i = 0; i < 8; ++i) outv[i] = (short)f2bf(acc8[i] * inv);
  *reinterpret_cast<bf16x8*>(Ab + ((size_t)b * 2048 + q0 + col) * 1024 + h * 64 + dh0) = outv;
}

extern "C" void kernel_launch(void* const* d_in, const int* in_sizes, int n_in,
                              void* d_out, int out_size, void* d_ws, size_t ws_size,
                              hipStream_t stream) {
  const float* x      = (const float*)d_in[0];
  const float* W_attn = (const float*)d_in[1];
  const float* b_attn = (const float*)d_in[2];
  const float* W_proj = (const float*)d_in[3];
  const float* b_proj = (const float*)d_in[4];
  float* out = (float*)d_out;

  u16* xb  = (u16*)d_ws;                      // [4096][1024] bf16
  u16* Wat = xb + (size_t)4096 * 1024;        // [3072][1024] bf16 (W_attn^T)
  u16* Wpt = Wat + (size_t)3072 * 1024;       // [1024][1024] bf16 (W_proj^T)
  u16* Qh  = Wpt + (size_t)1024 * 1024;       // [2,16,2048,64] bf16 (log2e/8-scaled)
  u16* Kh  = Qh + (size_t)4194304;            // [2,16,2048,64] bf16
  u16* VhT = Kh + (size_t)4194304;            // [2,16,64,2048] bf16
  u16* Ab  = VhT + (size_t)4194304;           // [4096][1024] bf16
  u16* Vh  = Ab;                              // [2,16,2048,64] bf16 (reuses Ab slot:
                                              //  consumed by transpose_v before attn writes Ab)

  cast_bf16_kernel<<<4096, 256, 0, stream>>>(x, xb, 4096 * 1024 / 4);
  transpose_cast<<<dim3(96, 32), dim3(32, 8), 0, stream>>>(W_attn, Wat, 1024, 3072);
  transpose_cast<<<dim3(32, 32), dim3(32, 8), 0, stream>>>(W_proj, Wpt, 1024, 1024);
  gemm_qkv<<<dim3(24, 32), 256, 0, stream>>>(xb, Wat, b_attn, Qh, Kh, Vh, 1024);
  transpose_v<<<dim3(32, 32), 256, 0, stream>>>(Vh, VhT);
  attn_fwd<<<dim3(2048), 256, 0, stream>>>(Qh, Kh, VhT, Ab);
  gemm_proj<<<dim3(16, 32), 256, 0, stream>>>(Ab, Wpt, b_proj, out, 1024, 1024);
}

// Round 8
// 213.530 us; speedup vs baseline: 1.0645x; 1.0216x over previous
//
#include <hip/hip_runtime.h>
#include <hip/hip_bf16.h>

// GPT attention block on MI355X: prep (cast+transposes) -> qkv GEMM -> causal
// flash attn -> proj GEMM.  B=2, T=2048, D=1024, H=16, dh=64.
// Attn: swapped-QK 32x32x16 MFMA, in-register exp2 softmax, cvt_pk P-pack (T12),
// defer-rescale (T13), setprio (T5), split-KV + LDS combine, permlane32_swap
// cross-lane reduce (no LDS on softmax chain).

typedef unsigned short u16;
typedef unsigned int u32;
typedef __attribute__((ext_vector_type(4))) float f32x4;
typedef __attribute__((ext_vector_type(16))) float f32x16;
typedef __attribute__((ext_vector_type(8))) short bf16x8;
typedef __attribute__((ext_vector_type(4))) int i32x4;

__device__ __forceinline__ u16 f2bf(float f) {
  unsigned u = __builtin_bit_cast(unsigned, f);
  u += 0x7FFFu + ((u >> 16) & 1u);
  return (u16)(u >> 16);
}

__device__ __forceinline__ u32 cvtpk(float lo, float hi) {
  u32 r;
  asm("v_cvt_pk_bf16_f32 %0, %1, %2" : "=v"(r) : "v"(lo), "v"(hi));
  return r;
}

// cross-32 exchange: returns {partner, own} (order per-lane unknown, set exact)
__device__ __forceinline__ void xc32(float x, float& y0, float& y1) {
  u32 xu = __builtin_bit_cast(u32, x);
  auto sw = __builtin_amdgcn_permlane32_swap(xu, xu, false, false);
  y0 = __builtin_bit_cast(float, (u32)sw[0]);
  y1 = __builtin_bit_cast(float, (u32)sw[1]);
}

__device__ __forceinline__ void gl_lds16(const u16* g, u16* l) {
  __builtin_amdgcn_global_load_lds(
      (const __attribute__((address_space(1))) void*)g,
      (__attribute__((address_space(3))) void*)l, 16, 0, 0);
}

// ---------------- prep: cast x -> bf16, transpose-cast W_attn / W_proj ----------------
// grid 8192: [0,4096) cast, [4096,7168) W_attn^T, [7168,8192) W_proj^T
__global__ __launch_bounds__(256) void prep(const float* __restrict__ x, u16* __restrict__ xb,
                                            const float* __restrict__ Wa, u16* __restrict__ Wat,
                                            const float* __restrict__ Wp, u16* __restrict__ Wpt) {
  __shared__ float tile[32][33];
  const int blk = blockIdx.x;
  const int tid = threadIdx.x;
  if (blk < 4096) {
    const int i = blk * 256 + tid;
    float4 f = reinterpret_cast<const float4*>(x)[i];
    ushort4 o;
    o.x = f2bf(f.x); o.y = f2bf(f.y); o.z = f2bf(f.z); o.w = f2bf(f.w);
    reinterpret_cast<ushort4*>(xb)[i] = o;
    return;
  }
  const float* in;
  u16* out;
  int R, C, bx, by;
  if (blk < 4096 + 3072) {
    const int bb = blk - 4096;
    in = Wa; out = Wat; R = 1024; C = 3072;
    bx = bb % 96; by = bb / 96;
  } else {
    const int bb = blk - 7168;
    in = Wp; out = Wpt; R = 1024; C = 1024;
    bx = bb % 32; by = bb / 32;
  }
  const int c0 = bx * 32, r0 = by * 32;
  const int tx = tid & 31, ty = tid >> 5;
#pragma unroll
  for (int i = 0; i < 4; ++i)
    tile[ty + 8 * i][tx] = in[(size_t)(r0 + ty + 8 * i) * C + c0 + tx];
  __syncthreads();
#pragma unroll
  for (int i = 0; i < 4; ++i)
    out[(size_t)(c0 + ty + 8 * i) * R + r0 + tx] = f2bf(tile[tx][ty + 8 * i]);
}

// ---------------- bf16 GEMM 128x128: qkv projection, scatter epilogue ----------------
// Writes Qh (scaled log2e/8) [B,H,T,dh], Kh [B,H,T,dh], VhT [B,H,dh,T].
__global__ __launch_bounds__(256) void gemm_qkv(
    const u16* __restrict__ A, const u16* __restrict__ Bt, const float* __restrict__ bias,
    u16* __restrict__ Qh, u16* __restrict__ Kh, u16* __restrict__ VhT, int K) {
  __shared__ u16 As[128 * 32];
  __shared__ u16 Bs[128 * 32];
  const int tid = threadIdx.x;
  const int wave = tid >> 6, lane = tid & 63;
  const int kg = lane >> 4, rr = lane & 15;
  const int wm = wave >> 1, wn = wave & 1;
  const int nwg = gridDim.x * gridDim.y;  // 768, %8==0
  const int lin = blockIdx.y * gridDim.x + blockIdx.x;
  const int swz = (lin & 7) * (nwg >> 3) + (lin >> 3);
  const int bx = swz % gridDim.x, by = swz / gridDim.x;
  const int rowA0 = by * 128, colB0 = bx * 128;

  const f32x4 z4 = {0.f, 0.f, 0.f, 0.f};
  f32x4 acc[4][4];
#pragma unroll
  for (int i = 0; i < 4; ++i)
#pragma unroll
    for (int j = 0; j < 4; ++j) acc[i][j] = z4;

  const int r_st = tid >> 2;
  const int c_st = (tid & 3) * 8;

  for (int k0 = 0; k0 < K; k0 += 32) {
#pragma unroll
    for (int i = 0; i < 2; ++i) {
      gl_lds16(A + (size_t)(rowA0 + i * 64 + r_st) * K + k0 + c_st,
               As + (i * 256 + (wave << 6)) * 8);
      gl_lds16(Bt + (size_t)(colB0 + i * 64 + r_st) * K + k0 + c_st,
               Bs + (i * 256 + (wave << 6)) * 8);
    }
    __syncthreads();

    bf16x8 af[4], bfr[4];
#pragma unroll
    for (int mi = 0; mi < 4; ++mi)
      af[mi] = *reinterpret_cast<const bf16x8*>(&As[(wm * 64 + mi * 16 + rr) * 32 + kg * 8]);
#pragma unroll
    for (int ni = 0; ni < 4; ++ni)
      bfr[ni] = *reinterpret_cast<const bf16x8*>(&Bs[(wn * 64 + ni * 16 + rr) * 32 + kg * 8]);
#pragma unroll
    for (int mi = 0; mi < 4; ++mi)
#pragma unroll
      for (int ni = 0; ni < 4; ++ni)
        acc[mi][ni] = __builtin_amdgcn_mfma_f32_16x16x32_bf16(af[mi], bfr[ni], acc[mi][ni], 0, 0, 0);
    __syncthreads();
  }

  const float QS = 0.125f * 1.44269504088896f;  // fold 1/sqrt(dh) * log2(e)
#pragma unroll
  for (int mi = 0; mi < 4; ++mi) {
#pragma unroll
    for (int ni = 0; ni < 4; ++ni) {
      const int col = colB0 + wn * 64 + ni * 16 + rr;
      const float bcol = bias[col];
      f32x4 a = acc[mi][ni];
#pragma unroll
      for (int v = 0; v < 4; ++v) {
        const int row = rowA0 + wm * 64 + mi * 16 + kg * 4 + v;
        const float val = a[v] + bcol;
        const int b = row >> 11, t = row & 2047;
        const int which = col >> 10, d = col & 1023;
        const int h = d >> 6, dd = d & 63;
        const size_t bh = (size_t)(b * 16 + h);
        if (which == 0)
          Qh[(bh * 2048 + t) * 64 + dd] = f2bf(val * QS);
        else if (which == 1)
          Kh[(bh * 2048 + t) * 64 + dd] = f2bf(val);
        else
          VhT[(bh * 64 + dd) * 2048 + t] = f2bf(val);
      }
    }
  }
}

// ---------------- bf16 GEMM 128x64: proj, fp32 out + bias ----------------
__global__ __launch_bounds__(256) void gemm_proj(
    const u16* __restrict__ A, const u16* __restrict__ Bt, const float* __restrict__ bias,
    float* __restrict__ outF, int N, int K) {
  __shared__ u16 As[128 * 32];
  __shared__ u16 Bs[64 * 32];
  const int tid = threadIdx.x;
  const int wave = tid >> 6, lane = tid & 63;
  const int kg = lane >> 4, rr = lane & 15;
  const int nwg = gridDim.x * gridDim.y;  // 512, %8==0
  const int lin = blockIdx.y * gridDim.x + blockIdx.x;
  const int swz = (lin & 7) * (nwg >> 3) + (lin >> 3);
  const int bx = swz % gridDim.x, by = swz / gridDim.x;
  const int rowA0 = by * 128, colB0 = bx * 64;

  const f32x4 z4 = {0.f, 0.f, 0.f, 0.f};
  f32x4 acc[2][4];
#pragma unroll
  for (int i = 0; i < 2; ++i)
#pragma unroll
    for (int j = 0; j < 4; ++j) acc[i][j] = z4;

  const int r_st = tid >> 2;
  const int c_st = (tid & 3) * 8;

  for (int k0 = 0; k0 < K; k0 += 32) {
#pragma unroll
    for (int i = 0; i < 2; ++i)
      gl_lds16(A + (size_t)(rowA0 + i * 64 + r_st) * K + k0 + c_st,
               As + (i * 256 + (wave << 6)) * 8);
    gl_lds16(Bt + (size_t)(colB0 + r_st) * K + k0 + c_st, Bs + (wave << 6) * 8);
    __syncthreads();

    bf16x8 af[2], bfr[4];
#pragma unroll
    for (int mi = 0; mi < 2; ++mi)
      af[mi] = *reinterpret_cast<const bf16x8*>(&As[(wave * 32 + mi * 16 + rr) * 32 + kg * 8]);
#pragma unroll
    for (int ni = 0; ni < 4; ++ni)
      bfr[ni] = *reinterpret_cast<const bf16x8*>(&Bs[(ni * 16 + rr) * 32 + kg * 8]);
#pragma unroll
    for (int mi = 0; mi < 2; ++mi)
#pragma unroll
      for (int ni = 0; ni < 4; ++ni)
        acc[mi][ni] = __builtin_amdgcn_mfma_f32_16x16x32_bf16(af[mi], bfr[ni], acc[mi][ni], 0, 0, 0);
    __syncthreads();
  }

#pragma unroll
  for (int mi = 0; mi < 2; ++mi) {
#pragma unroll
    for (int ni = 0; ni < 4; ++ni) {
      const int col = colB0 + ni * 16 + rr;
      const float bcol = bias[col];
      f32x4 a = acc[mi][ni];
#pragma unroll
      for (int v = 0; v < 4; ++v) {
        const int row = rowA0 + wave * 32 + mi * 16 + kg * 4 + v;
        outF[(size_t)row * N + col] = a[v] + bcol;
      }
    }
  }
}

// ---------------- attn step ----------------
__device__ __forceinline__ void load_k(const u16* kptr, bf16x8 (&kA)[4], bf16x8 (&kB)[4]) {
#pragma unroll
  for (int ks = 0; ks < 4; ++ks) {
    kA[ks] = *reinterpret_cast<const bf16x8*>(kptr + ks * 16);
    kB[ks] = *reinterpret_cast<const bf16x8*>(kptr + 2048 + ks * 16);
  }
}

__device__ __forceinline__ void attn_step(
    int kvb, int n64, int myq, int hi, const u16* vbase,
    const bf16x8 (&qf)[4], const bf16x8 (&kA)[4], const bf16x8 (&kB)[4],
    f32x16& oA, f32x16& oB, float& m, float& l) {
  // V loads issued FIRST: latency hides under QK^T + softmax
  bf16x8 vfA[4], vfB[4];
  const u16* vp = vbase + kvb * 64;
#pragma unroll
  for (int ks = 0; ks < 4; ++ks) {
    vfA[ks] = *reinterpret_cast<const bf16x8*>(vp + ks * 16);
    vfB[ks] = *reinterpret_cast<const bf16x8*>(vp + 32 * 2048 + ks * 16);
  }

  // S^T = K Q^T (log2 domain): col=q, row kv = (r&3)+8*(r>>2)+4*hi
  f32x16 sA, sB;
#pragma unroll
  for (int i = 0; i < 16; ++i) { sA[i] = 0.f; sB[i] = 0.f; }
  __builtin_amdgcn_s_setprio(1);
#pragma unroll
  for (int ks = 0; ks < 4; ++ks)
    sA = __builtin_amdgcn_mfma_f32_32x32x16_bf16(kA[ks], qf[ks], sA, 0, 0, 0);
#pragma unroll
  for (int ks = 0; ks < 4; ++ks)
    sB = __builtin_amdgcn_mfma_f32_32x32x16_bf16(kB[ks], qf[ks], sB, 0, 0, 0);
  __builtin_amdgcn_s_setprio(0);

  if (kvb == n64 - 1) {  // causal mask, last global block only
    const int kv0 = kvb * 64;
#pragma unroll
    for (int r = 0; r < 16; ++r) {
      const int kvA = kv0 + (r & 3) + 8 * (r >> 2) + 4 * hi;
      if (kvA > myq) sA[r] = -1e30f;
      if (kvA + 32 > myq) sB[r] = -1e30f;
    }
  }

  // online softmax (log2 domain); cross-32 exchange via permlane32_swap (VALU)
  float pmax = -1e30f;
#pragma unroll
  for (int r = 0; r < 16; ++r) pmax = fmaxf(pmax, fmaxf(sA[r], sB[r]));
  {
    float y0, y1;
    xc32(pmax, y0, y1);
    pmax = fmaxf(y0, y1);  // {y0,y1} = {own,partner}
  }
  if (!__all(pmax - m <= 8.0f)) {  // T13 defer-rescale (p bounded by 2^8)
    const float mn = fmaxf(m, pmax);
    const float sc = __builtin_amdgcn_exp2f(m - mn);
    l *= sc;
    oA *= sc;
    oB *= sc;
    m = mn;
  }
  float rsum = 0.f;
#pragma unroll
  for (int r = 0; r < 16; ++r) {
    const float pa = __builtin_amdgcn_exp2f(sA[r] - m);
    const float pb = __builtin_amdgcn_exp2f(sB[r] - m);
    sA[r] = pa; sB[r] = pb;
    rsum += pa + pb;
  }
  {
    float y0, y1;
    xc32(rsum, y0, y1);
    rsum = y0 + y1;  // own + partner
  }
  l += rsum;

  // P^T -> bf16 B-operand frags: v_cvt_pk + permlane32_swap (T12)
  u32 pkA[8], pkB[8];
#pragma unroll
  for (int i = 0; i < 8; ++i) {
    pkA[i] = cvtpk(sA[2 * i], sA[2 * i + 1]);
    pkB[i] = cvtpk(sB[2 * i], sB[2 * i + 1]);
  }
  bf16x8 pf[4];
  {
    auto w0 = __builtin_amdgcn_permlane32_swap(pkA[0], pkA[2], false, false);
    auto w1 = __builtin_amdgcn_permlane32_swap(pkA[1], pkA[3], false, false);
    i32x4 t0 = {(int)w0[0], (int)w1[0], (int)w0[1], (int)w1[1]};
    pf[0] = __builtin_bit_cast(bf16x8, t0);
    auto w2 = __builtin_amdgcn_permlane32_swap(pkA[4], pkA[6], false, false);
    auto w3 = __builtin_amdgcn_permlane32_swap(pkA[5], pkA[7], false, false);
    i32x4 t1 = {(int)w2[0], (int)w3[0], (int)w2[1], (int)w3[1]};
    pf[1] = __builtin_bit_cast(bf16x8, t1);
    auto w4 = __builtin_amdgcn_permlane32_swap(pkB[0], pkB[2], false, false);
    auto w5 = __builtin_amdgcn_permlane32_swap(pkB[1], pkB[3], false, false);
    i32x4 t2 = {(int)w4[0], (int)w5[0], (int)w4[1], (int)w5[1]};
    pf[2] = __builtin_bit_cast(bf16x8, t2);
    auto w6 = __builtin_amdgcn_permlane32_swap(pkB[4], pkB[6], false, false);
    auto w7 = __builtin_amdgcn_permlane32_swap(pkB[5], pkB[7], false, false);
    i32x4 t3 = {(int)w6[0], (int)w7[0], (int)w6[1], (int)w7[1]};
    pf[3] = __builtin_bit_cast(bf16x8, t3);
  }

  // O^T += V^T P^T
  __builtin_amdgcn_s_setprio(1);
#pragma unroll
  for (int ks = 0; ks < 4; ++ks)
    oA = __builtin_amdgcn_mfma_f32_32x32x16_bf16(vfA[ks], pf[ks], oA, 0, 0, 0);
#pragma unroll
  for (int ks = 0; ks < 4; ++ks)
    oB = __builtin_amdgcn_mfma_f32_32x32x16_bf16(vfB[ks], pf[ks], oB, 0, 0, 0);
  __builtin_amdgcn_s_setprio(0);
}

// ---------------- causal flash attention, split-KV + pipelined K loads ----------------
__global__ __launch_bounds__(256, 2) void attn_fwd(const u16* __restrict__ Qh,
                                                   const u16* __restrict__ Kh,
                                                   const u16* __restrict__ VhT,
                                                   u16* __restrict__ Ab) {
  __shared__ u16 Olq[4][32][72];   // [wave][q][dh 64 + pad8], bf16 partials
  __shared__ float Ml[4][2][32];   // [wave][{m,l}][q]
  const int tid = threadIdx.x;
  const int wave = tid >> 6, lane = tid & 63;
  const int lq = lane & 31, hi = lane >> 5;
  const int blk = blockIdx.x;
  const int qi = blk >> 5;          // 0..63, longest qtile first
  const int bh = blk & 31;
  const int qtile = 63 - qi;
  const int q0 = qtile * 32;
  const int myq = q0 + lq;
  const size_t kvbase = (size_t)bh * 2048;

  const int n64 = (q0 + 32 + 63) >> 6;
  const int base = n64 >> 2, rem = n64 & 3;
  const int cnt = base + (wave < rem ? 1 : 0);
  const int start = wave * base + (wave < rem ? wave : rem);
  const int end = start + cnt;

  // Q as B-operand (pre-scaled by log2e/8): col=q, k = hi*8 + j (+16*ks)
  bf16x8 qf[4];
  {
    const u16* qptr = Qh + (kvbase + q0 + lq) * 64 + hi * 8;
#pragma unroll
    for (int ks = 0; ks < 4; ++ks)
      qf[ks] = *reinterpret_cast<const bf16x8*>(qptr + ks * 16);
  }

  f32x16 oA, oB;
#pragma unroll
  for (int i = 0; i < 16; ++i) { oA[i] = 0.f; oB[i] = 0.f; }
  float m = -1e30f, l = 0.f;

  const u16* kbase = Kh + (kvbase + lq) * 64 + hi * 8;              // + kvb*4096
  const u16* vbase = VhT + ((size_t)bh * 64 + lq) * 2048 + hi * 8;  // + kvb*64

  // software pipeline: K double-buffered in registers, 2-phase static unroll
  bf16x8 kA0[4], kB0[4], kA1[4], kB1[4];
  int kvb = start;
  if (kvb < end) {
    load_k(kbase + (size_t)kvb * 4096, kA0, kB0);
    while (true) {
      if (kvb + 1 < end) load_k(kbase + (size_t)(kvb + 1) * 4096, kA1, kB1);
      attn_step(kvb, n64, myq, hi, vbase, qf, kA0, kB0, oA, oB, m, l);
      if (++kvb >= end) break;
      if (kvb + 1 < end) load_k(kbase + (size_t)(kvb + 1) * 4096, kA0, kB0);
      attn_step(kvb, n64, myq, hi, vbase, qf, kA1, kB1, oA, oB, m, l);
      if (++kvb >= end) break;
    }
  }

  // ---- write partials (bf16, vectorized) ----
  if (hi == 0) {
    Ml[wave][0][lq] = m;
    Ml[wave][1][lq] = l;
  }
  {
    u32* orow = reinterpret_cast<u32*>(&Olq[wave][lq][0]);
#pragma unroll
    for (int qd = 0; qd < 4; ++qd) {
      const int dh0 = 8 * qd + 4 * hi;  // even -> u32-aligned
      orow[(dh0 >> 1) + 0] = cvtpk(oA[4 * qd + 0], oA[4 * qd + 1]);
      orow[(dh0 >> 1) + 1] = cvtpk(oA[4 * qd + 2], oA[4 * qd + 3]);
      orow[((dh0 + 32) >> 1) + 0] = cvtpk(oB[4 * qd + 0], oB[4 * qd + 1]);
      orow[((dh0 + 32) >> 1) + 1] = cvtpk(oB[4 * qd + 2], oB[4 * qd + 3]);
    }
  }
  __syncthreads();

  // ---- combine: thread -> (q-col = tid>>3, dh0 = (tid&7)*8) ----
  const int col = tid >> 3;
  const int dh0 = (tid & 7) * 8;
  float M = -1e30f;
  float mw[4];
#pragma unroll
  for (int w = 0; w < 4; ++w) { mw[w] = Ml[w][0][col]; M = fmaxf(M, mw[w]); }
  float lsum = 0.f;
  float scw[4];
#pragma unroll
  for (int w = 0; w < 4; ++w) {
    scw[w] = __builtin_amdgcn_exp2f(mw[w] - M);
    lsum += scw[w] * Ml[w][1][col];
  }
  const float inv = 1.0f / lsum;
  float acc8[8];
#pragma unroll
  for (int i = 0; i < 8; ++i) acc8[i] = 0.f;
#pragma unroll
  for (int w = 0; w < 4; ++w) {
    bf16x8 ov = *reinterpret_cast<const bf16x8*>(&Olq[w][col][dh0]);
#pragma unroll
    for (int i = 0; i < 8; ++i) {
      const float f = __builtin_bit_cast(float, ((u32)(u16)ov[i]) << 16);
      acc8[i] += scw[w] * f;
    }
  }
  const int b = bh >> 4, h = bh & 15;
  bf16x8 outv;
#pragma unroll
  for (int i = 0; i < 8; ++i) outv[i] = (short)f2bf(acc8[i] * inv);
  *reinterpret_cast<bf16x8*>(Ab + ((size_t)b * 2048 + q0 + col) * 1024 + h * 64 + dh0) = outv;
}

extern "C" void kernel_launch(void* const* d_in, const int* in_sizes, int n_in,
                              void* d_out, int out_size, void* d_ws, size_t ws_size,
                              hipStream_t stream) {
  const float* x      = (const float*)d_in[0];
  const float* W_attn = (const float*)d_in[1];
  const float* b_attn = (const float*)d_in[2];
  const float* W_proj = (const float*)d_in[3];
  const float* b_proj = (const float*)d_in[4];
  float* out = (float*)d_out;

  u16* xb  = (u16*)d_ws;                      // [4096][1024] bf16
  u16* Wat = xb + (size_t)4096 * 1024;        // [3072][1024] bf16 (W_attn^T)
  u16* Wpt = Wat + (size_t)3072 * 1024;       // [1024][1024] bf16 (W_proj^T)
  u16* Qh  = Wpt + (size_t)1024 * 1024;       // [2,16,2048,64] bf16 (log2e/8-scaled)
  u16* Kh  = Qh + (size_t)4194304;            // [2,16,2048,64] bf16
  u16* VhT = Kh + (size_t)4194304;            // [2,16,64,2048] bf16
  u16* Ab  = VhT + (size_t)4194304;           // [4096][1024] bf16

  prep<<<8192, 256, 0, stream>>>(x, xb, W_attn, Wat, W_proj, Wpt);
  gemm_qkv<<<dim3(24, 32), 256, 0, stream>>>(xb, Wat, b_attn, Qh, Kh, VhT, 1024);
  attn_fwd<<<dim3(2048), 256, 0, stream>>>(Qh, Kh, VhT, Ab);
  gemm_proj<<<dim3(16, 32), 256, 0, stream>>>(Ab, Wpt, b_proj, out, 1024, 1024);
}